// Round 1
// baseline (3247.989 us; speedup 1.0000x reference)
//
#include <hip/hip_runtime.h>

// LightGCN encoder: acc = (A·e0 + A²·e0 + A³·e0)/3, A is 600K-edge COO scatter.
constexpr int USER_NUM = 100000;
constexpr int ITEM_NUM = 50000;
constexpr int N_NODES  = USER_NUM + ITEM_NUM;
constexpr int EMB      = 128;
constexpr int N_EDGES  = 600000;

// One edge per 32 threads; each thread gathers a float4 of x[col] and
// atomically adds v*g into out[row]. Rows are random (deg~4) -> low contention.
__global__ void spmm_first(const float* __restrict__ user_emb,
                           const float* __restrict__ item_emb,
                           const float* __restrict__ ev,
                           const int* __restrict__ er,
                           const int* __restrict__ ec,
                           float* __restrict__ out) {
    int tid  = blockIdx.x * blockDim.x + threadIdx.x;
    int edge = tid >> 5;
    if (edge >= N_EDGES) return;
    int lane = tid & 31;
    int row = er[edge];
    int col = ec[edge];
    float v = ev[edge];
    const float* x = (col < USER_NUM)
        ? (user_emb + (size_t)col * EMB)
        : (item_emb + (size_t)(col - USER_NUM) * EMB);
    float4 g = ((const float4*)x)[lane];
    float* o = out + (size_t)row * EMB + lane * 4;
    atomicAdd(o + 0, v * g.x);
    atomicAdd(o + 1, v * g.y);
    atomicAdd(o + 2, v * g.z);
    atomicAdd(o + 3, v * g.w);
}

__global__ void spmm(const float* __restrict__ x,
                     const float* __restrict__ ev,
                     const int* __restrict__ er,
                     const int* __restrict__ ec,
                     float* __restrict__ out) {
    int tid  = blockIdx.x * blockDim.x + threadIdx.x;
    int edge = tid >> 5;
    if (edge >= N_EDGES) return;
    int lane = tid & 31;
    int row = er[edge];
    int col = ec[edge];
    float v = ev[edge];
    float4 g = ((const float4*)(x + (size_t)col * EMB))[lane];
    float* o = out + (size_t)row * EMB + lane * 4;
    atomicAdd(o + 0, v * g.x);
    atomicAdd(o + 1, v * g.y);
    atomicAdd(o + 2, v * g.z);
    atomicAdd(o + 3, v * g.w);
}

// acc = (acc + cur) * scale, vectorized float4 streaming pass.
__global__ void acc_add(float* __restrict__ acc,
                        const float* __restrict__ cur,
                        float scale, int n4) {
    int i = blockIdx.x * blockDim.x + threadIdx.x;
    if (i >= n4) return;
    float4 a = ((const float4*)acc)[i];
    float4 c = ((const float4*)cur)[i];
    a.x = (a.x + c.x) * scale;
    a.y = (a.y + c.y) * scale;
    a.z = (a.z + c.z) * scale;
    a.w = (a.w + c.w) * scale;
    ((float4*)acc)[i] = a;
}

extern "C" void kernel_launch(void* const* d_in, const int* in_sizes, int n_in,
                              void* d_out, int out_size, void* d_ws, size_t ws_size,
                              hipStream_t stream) {
    const float* user_emb = (const float*)d_in[0];
    const float* item_emb = (const float*)d_in[1];
    const float* ev       = (const float*)d_in[2];
    const int*   er       = (const int*)d_in[3];
    const int*   ec       = (const int*)d_in[4];
    float* acc = (float*)d_out;                 // acc doubles as the output

    size_t nfloats = (size_t)N_NODES * EMB;     // 19.2M floats = 76.8 MB
    float* buf0 = (float*)d_ws;
    float* buf1 = buf0 + nfloats;

    const int BLOCK = 256;
    const int spmm_blocks = (N_EDGES * 32) / BLOCK;       // 75000
    const int n4 = (int)(nfloats / 4);                    // 4.8M
    const int add_blocks = (n4 + BLOCK - 1) / BLOCK;

    // acc starts at 0 (harness poisons d_out/d_ws with 0xAA every call)
    hipMemsetAsync(acc, 0, nfloats * sizeof(float), stream);

    // layer 1: e1 = A * e0 (e0 read straight from the two input tables)
    hipMemsetAsync(buf0, 0, nfloats * sizeof(float), stream);
    spmm_first<<<spmm_blocks, BLOCK, 0, stream>>>(user_emb, item_emb, ev, er, ec, buf0);
    acc_add<<<add_blocks, BLOCK, 0, stream>>>(acc, buf0, 1.0f, n4);

    // layer 2: e2 = A * e1
    hipMemsetAsync(buf1, 0, nfloats * sizeof(float), stream);
    spmm<<<spmm_blocks, BLOCK, 0, stream>>>(buf0, ev, er, ec, buf1);
    acc_add<<<add_blocks, BLOCK, 0, stream>>>(acc, buf1, 1.0f, n4);

    // layer 3: e3 = A * e2 (buf0 is dead after layer 2, reuse it)
    hipMemsetAsync(buf0, 0, nfloats * sizeof(float), stream);
    spmm<<<spmm_blocks, BLOCK, 0, stream>>>(buf1, ev, er, ec, buf0);
    // final fold: acc = (e1 + e2 + e3) / 3
    acc_add<<<add_blocks, BLOCK, 0, stream>>>(acc, buf0, 1.0f / 3.0f, n4);
}

// Round 2
// 457.267 us; speedup vs baseline: 7.1030x; 7.1030x over previous
//
#include <hip/hip_runtime.h>

// LightGCN encoder: acc = (A·e0 + A²·e0 + A³·e0)/3, A is 600K-edge COO.
// R2: CSR-gather SpMM (no atomics in the hot path). CSR built on-device
// each call: histogram -> block scan -> scatter (col,val) into row-sorted
// order. Each row is then reduced by 32 lanes with float4 gathers and a
// single streamed write; the layer accumulator is fused into the epilogue.
constexpr int USER_NUM = 100000;
constexpr int ITEM_NUM = 50000;
constexpr int N_NODES  = USER_NUM + ITEM_NUM;
constexpr int EMB      = 128;
constexpr int N_EDGES  = 600000;
constexpr int SCAN_BS  = 1024;

// ---------------- CSR build ----------------
__global__ void hist_k(const int* __restrict__ er, int* __restrict__ cnt) {
    int e = blockIdx.x * 256 + threadIdx.x;
    if (e < N_EDGES) atomicAdd(&cnt[er[e]], 1);
}

// in-place per-block exclusive scan of cnt[0..N_NODES), block sums to bsum
__global__ void scan1_k(int* __restrict__ data, int* __restrict__ bsum) {
    __shared__ int sh[SCAN_BS];
    int i = blockIdx.x * SCAN_BS + threadIdx.x;
    int v = (i < N_NODES) ? data[i] : 0;
    sh[threadIdx.x] = v;
    __syncthreads();
    for (int off = 1; off < SCAN_BS; off <<= 1) {
        int t = (threadIdx.x >= off) ? sh[threadIdx.x - off] : 0;
        __syncthreads();
        sh[threadIdx.x] += t;
        __syncthreads();
    }
    if (i < N_NODES) data[i] = sh[threadIdx.x] - v;   // exclusive
    if (threadIdx.x == SCAN_BS - 1) bsum[blockIdx.x] = sh[threadIdx.x];
}

// serial scan of ~147 block sums (trivial cost)
__global__ void scan2_k(int* __restrict__ bsum, int nb) {
    if (threadIdx.x == 0 && blockIdx.x == 0) {
        int run = 0;
        for (int b = 0; b < nb; ++b) { int t = bsum[b]; bsum[b] = run; run += t; }
    }
}

__global__ void scan3_k(int* __restrict__ start, int* __restrict__ cursor,
                        const int* __restrict__ bsum) {
    int i = blockIdx.x * 256 + threadIdx.x;
    if (i < N_NODES) {
        int s = start[i] + bsum[i >> 10];
        start[i] = s;
        cursor[i] = s;
    }
    if (i == 0) start[N_NODES] = N_EDGES;
}

__global__ void scatter_k(const int* __restrict__ er, const int* __restrict__ ec,
                          const float* __restrict__ ev,
                          int* __restrict__ cursor, int* __restrict__ sc,
                          float* __restrict__ sv) {
    int e = blockIdx.x * 256 + threadIdx.x;
    if (e >= N_EDGES) return;
    int p = atomicAdd(&cursor[er[e]], 1);
    sc[p] = ec[e];
    sv[p] = ev[e];
}

// ---------------- gather SpMM, acc fused ----------------
// MODE 0: layer1, x from the two input tables; outbuf=e1; acc = s
// MODE 1: layer2, x=buf;                       outbuf=e2; acc += s
// MODE 2: layer3, x=buf; no outbuf;            acc = (acc + s)/3
template <int MODE>
__global__ __launch_bounds__(256) void spmm_gather(
        const float4* __restrict__ x,
        const float4* __restrict__ ue, const float4* __restrict__ ie,
        const int* __restrict__ start, const int* __restrict__ sc,
        const float* __restrict__ sv,
        float4* __restrict__ outbuf, float4* __restrict__ acc) {
    int row  = blockIdx.x * 8 + (threadIdx.x >> 5);   // 8 rows per 256-block
    int lane = threadIdx.x & 31;                      // float4 slice of EMB
    int e0 = start[row], e1 = start[row + 1];
    float4 s = make_float4(0.f, 0.f, 0.f, 0.f);
    for (int e = e0; e < e1; ++e) {
        int c   = sc[e];
        float v = sv[e];
        const float4* xs;
        if (MODE == 0)
            xs = (c < USER_NUM) ? (ue + (size_t)c * 32)
                                : (ie + (size_t)(c - USER_NUM) * 32);
        else
            xs = x + (size_t)c * 32;
        float4 g = xs[lane];
        s.x += v * g.x; s.y += v * g.y; s.z += v * g.z; s.w += v * g.w;
    }
    size_t o = (size_t)row * 32 + lane;
    if (MODE < 2) outbuf[o] = s;
    if (MODE == 0) {
        acc[o] = s;
    } else if (MODE == 1) {
        float4 a = acc[o];
        a.x += s.x; a.y += s.y; a.z += s.z; a.w += s.w;
        acc[o] = a;
    } else {
        float4 a = acc[o];
        const float k = 1.0f / 3.0f;
        a.x = (a.x + s.x) * k; a.y = (a.y + s.y) * k;
        a.z = (a.z + s.z) * k; a.w = (a.w + s.w) * k;
        acc[o] = a;
    }
}

// ---------------- fallback (R1 atomic path, used only if ws too small) ----
__global__ void spmm_first_at(const float* __restrict__ ue, const float* __restrict__ ie,
                              const float* __restrict__ ev, const int* __restrict__ er,
                              const int* __restrict__ ec, float* __restrict__ out) {
    int tid = blockIdx.x * blockDim.x + threadIdx.x;
    int edge = tid >> 5;
    if (edge >= N_EDGES) return;
    int lane = tid & 31;
    int row = er[edge]; int col = ec[edge]; float v = ev[edge];
    const float* x = (col < USER_NUM) ? (ue + (size_t)col * EMB)
                                      : (ie + (size_t)(col - USER_NUM) * EMB);
    float4 g = ((const float4*)x)[lane];
    float* o = out + (size_t)row * EMB + lane * 4;
    atomicAdd(o + 0, v * g.x); atomicAdd(o + 1, v * g.y);
    atomicAdd(o + 2, v * g.z); atomicAdd(o + 3, v * g.w);
}
__global__ void spmm_at(const float* __restrict__ x, const float* __restrict__ ev,
                        const int* __restrict__ er, const int* __restrict__ ec,
                        float* __restrict__ out) {
    int tid = blockIdx.x * blockDim.x + threadIdx.x;
    int edge = tid >> 5;
    if (edge >= N_EDGES) return;
    int lane = tid & 31;
    int row = er[edge]; int col = ec[edge]; float v = ev[edge];
    float4 g = ((const float4*)(x + (size_t)col * EMB))[lane];
    float* o = out + (size_t)row * EMB + lane * 4;
    atomicAdd(o + 0, v * g.x); atomicAdd(o + 1, v * g.y);
    atomicAdd(o + 2, v * g.z); atomicAdd(o + 3, v * g.w);
}
__global__ void acc_add(float* __restrict__ acc, const float* __restrict__ cur,
                        float scale, int n4) {
    int i = blockIdx.x * blockDim.x + threadIdx.x;
    if (i >= n4) return;
    float4 a = ((const float4*)acc)[i];
    float4 c = ((const float4*)cur)[i];
    a.x = (a.x + c.x) * scale; a.y = (a.y + c.y) * scale;
    a.z = (a.z + c.z) * scale; a.w = (a.w + c.w) * scale;
    ((float4*)acc)[i] = a;
}

extern "C" void kernel_launch(void* const* d_in, const int* in_sizes, int n_in,
                              void* d_out, int out_size, void* d_ws, size_t ws_size,
                              hipStream_t stream) {
    const float* ue = (const float*)d_in[0];
    const float* ie = (const float*)d_in[1];
    const float* ev = (const float*)d_in[2];
    const int*   er = (const int*)d_in[3];
    const int*   ec = (const int*)d_in[4];
    float* acc = (float*)d_out;

    size_t nfloats = (size_t)N_NODES * EMB;           // 19.2M
    float* buf0 = (float*)d_ws;
    float* buf1 = buf0 + nfloats;

    const int nscan = (N_NODES + SCAN_BS - 1) / SCAN_BS;   // 147
    // CSR workspace after the two ping-pong buffers
    int*   start  = (int*)(buf1 + nfloats);           // N_NODES+1
    int*   cursor = start + (N_NODES + 1);            // N_NODES
    int*   sc     = cursor + N_NODES;                 // N_EDGES
    float* sv     = (float*)(sc + N_EDGES);           // N_EDGES
    int*   bsum   = (int*)(sv + N_EDGES);             // nscan
    size_t needed = (char*)(bsum + nscan) - (char*)d_ws;

    const int BLOCK = 256;
    const int eblocks = (N_EDGES + BLOCK - 1) / BLOCK;

    if (ws_size >= needed) {
        // ---- CSR build ----
        hipMemsetAsync(start, 0, (size_t)N_NODES * sizeof(int), stream);
        hist_k<<<eblocks, BLOCK, 0, stream>>>(er, start);
        scan1_k<<<nscan, SCAN_BS, 0, stream>>>(start, bsum);
        scan2_k<<<1, 64, 0, stream>>>(bsum, nscan);
        scan3_k<<<(N_NODES + BLOCK - 1) / BLOCK, BLOCK, 0, stream>>>(start, cursor, bsum);
        scatter_k<<<eblocks, BLOCK, 0, stream>>>(er, ec, ev, cursor, sc, sv);

        // ---- 3 gather layers, acc fused ----
        const int gblocks = N_NODES / 8;              // 18750, exact
        spmm_gather<0><<<gblocks, BLOCK, 0, stream>>>(
            nullptr, (const float4*)ue, (const float4*)ie, start, sc, sv,
            (float4*)buf0, (float4*)acc);
        spmm_gather<1><<<gblocks, BLOCK, 0, stream>>>(
            (const float4*)buf0, nullptr, nullptr, start, sc, sv,
            (float4*)buf1, (float4*)acc);
        spmm_gather<2><<<gblocks, BLOCK, 0, stream>>>(
            (const float4*)buf1, nullptr, nullptr, start, sc, sv,
            nullptr, (float4*)acc);
    } else {
        // ---- fallback: R1 atomic path ----
        const int spmm_blocks = (N_EDGES * 32) / BLOCK;
        const int n4 = (int)(nfloats / 4);
        const int add_blocks = (n4 + BLOCK - 1) / BLOCK;
        hipMemsetAsync(acc, 0, nfloats * sizeof(float), stream);
        hipMemsetAsync(buf0, 0, nfloats * sizeof(float), stream);
        spmm_first_at<<<spmm_blocks, BLOCK, 0, stream>>>(ue, ie, ev, er, ec, buf0);
        acc_add<<<add_blocks, BLOCK, 0, stream>>>(acc, buf0, 1.0f, n4);
        hipMemsetAsync(buf1, 0, nfloats * sizeof(float), stream);
        spmm_at<<<spmm_blocks, BLOCK, 0, stream>>>(buf0, ev, er, ec, buf1);
        acc_add<<<add_blocks, BLOCK, 0, stream>>>(acc, buf1, 1.0f, n4);
        hipMemsetAsync(buf0, 0, nfloats * sizeof(float), stream);
        spmm_at<<<spmm_blocks, BLOCK, 0, stream>>>(buf1, ev, er, ec, buf0);
        acc_add<<<add_blocks, BLOCK, 0, stream>>>(acc, buf0, 1.0f / 3.0f, n4);
    }
}

// Round 3
// 389.971 us; speedup vs baseline: 8.3288x; 1.1726x over previous
//
#include <hip/hip_runtime.h>

// LightGCN encoder: out = (A·e0 + A²·e0 + A³·e0)/3, A = 600K-edge COO.
// R3: CSR-gather SpMM. vs R2: (a) layer kernels write only their own layer
// buffer; the final layer folds acc=(e1+e2+e3)/3 in one pass (saves 154 MB
// of acc traffic), (b) scan2 is a wave shuffle-scan instead of 1 serial
// thread (~35us -> ~3us), (c) (col,val) packed as int2: one 8B random store
// in scatter / one 8B load in the gather loop instead of two 4B each.
constexpr int USER_NUM = 100000;
constexpr int ITEM_NUM = 50000;
constexpr int N_NODES  = USER_NUM + ITEM_NUM;
constexpr int EMB      = 128;
constexpr int N_EDGES  = 600000;
constexpr int SCAN_BS  = 1024;

// ---------------- CSR build ----------------
__global__ void hist_k(const int* __restrict__ er, int* __restrict__ cnt) {
    int e = blockIdx.x * 256 + threadIdx.x;
    if (e < N_EDGES) atomicAdd(&cnt[er[e]], 1);
}

// per-block exclusive scan of cnt[0..N_NODES), block totals to bsum
__global__ void scan1_k(int* __restrict__ data, int* __restrict__ bsum) {
    __shared__ int sh[SCAN_BS];
    int i = blockIdx.x * SCAN_BS + threadIdx.x;
    int v = (i < N_NODES) ? data[i] : 0;
    sh[threadIdx.x] = v;
    __syncthreads();
    for (int off = 1; off < SCAN_BS; off <<= 1) {
        int t = (threadIdx.x >= off) ? sh[threadIdx.x - off] : 0;
        __syncthreads();
        sh[threadIdx.x] += t;
        __syncthreads();
    }
    if (i < N_NODES) data[i] = sh[threadIdx.x] - v;   // exclusive
    if (threadIdx.x == SCAN_BS - 1) bsum[blockIdx.x] = sh[threadIdx.x];
}

// single-wave exclusive scan of nb (~147) block sums
__global__ void scan2_k(int* __restrict__ bsum, int nb) {
    int lane = threadIdx.x;           // one wave of 64
    int run = 0;
    for (int base = 0; base < nb; base += 64) {
        int i = base + lane;
        int orig = (i < nb) ? bsum[i] : 0;
        int v = orig;
        #pragma unroll
        for (int off = 1; off < 64; off <<= 1) {
            int t = __shfl_up(v, off, 64);
            if (lane >= off) v += t;
        }
        if (i < nb) bsum[i] = run + v - orig;         // exclusive
        run += __shfl(v, 63, 64);                     // chunk total
    }
}

__global__ void scan3_k(int* __restrict__ start, int* __restrict__ cursor,
                        const int* __restrict__ bsum) {
    int i = blockIdx.x * 256 + threadIdx.x;
    if (i < N_NODES) {
        int s = start[i] + bsum[i >> 10];
        start[i] = s;
        cursor[i] = s;
    }
    if (i == 0) start[N_NODES] = N_EDGES;
}

// scatter packed (col, val-bits) into row-sorted order: one 8B store/edge
__global__ void scatter_k(const int* __restrict__ er, const int* __restrict__ ec,
                          const float* __restrict__ ev,
                          int* __restrict__ cursor, int2* __restrict__ edges) {
    int e = blockIdx.x * 256 + threadIdx.x;
    if (e >= N_EDGES) return;
    int p = atomicAdd(&cursor[er[e]], 1);
    edges[p] = make_int2(ec[e], __float_as_int(ev[e]));
}

// ---------------- gather SpMM ----------------
// MODE 0: x from the two input tables; out = e1
// MODE 1: x = e1 buffer;               out = e2
// MODE 2: x = e2 buffer (gather + linear), b0 = e1; acc = (e1+e2+s)/3
template <int MODE>
__global__ __launch_bounds__(256) void spmm_gather(
        const float4* __restrict__ x,
        const float4* __restrict__ ue, const float4* __restrict__ ie,
        const int* __restrict__ start, const int2* __restrict__ edges,
        float4* __restrict__ out,
        const float4* __restrict__ b0, float4* __restrict__ acc) {
    int row  = blockIdx.x * 8 + (threadIdx.x >> 5);   // 8 rows / 256-block
    int lane = threadIdx.x & 31;                      // float4 slice of EMB
    int e0 = start[row], e1 = start[row + 1];
    float4 s = make_float4(0.f, 0.f, 0.f, 0.f);
    for (int e = e0; e < e1; ++e) {
        int2 p  = edges[e];
        float v = __int_as_float(p.y);
        const float4* xs;
        if (MODE == 0)
            xs = (p.x < USER_NUM) ? (ue + (size_t)p.x * 32)
                                  : (ie + (size_t)(p.x - USER_NUM) * 32);
        else
            xs = x + (size_t)p.x * 32;
        float4 g = xs[lane];
        s.x += v * g.x; s.y += v * g.y; s.z += v * g.z; s.w += v * g.w;
    }
    size_t o = (size_t)row * 32 + lane;
    if (MODE < 2) {
        out[o] = s;
    } else {
        float4 a0 = b0[o];          // e1, linear
        float4 a1 = x[o];           // e2, linear (LLC-warm)
        const float k = 1.0f / 3.0f;
        float4 r;
        r.x = (a0.x + a1.x + s.x) * k;
        r.y = (a0.y + a1.y + s.y) * k;
        r.z = (a0.z + a1.z + s.z) * k;
        r.w = (a0.w + a1.w + s.w) * k;
        acc[o] = r;
    }
}

// ---------------- fallback (atomic path, used only if ws too small) ----
__global__ void spmm_first_at(const float* __restrict__ ue, const float* __restrict__ ie,
                              const float* __restrict__ ev, const int* __restrict__ er,
                              const int* __restrict__ ec, float* __restrict__ out) {
    int tid = blockIdx.x * blockDim.x + threadIdx.x;
    int edge = tid >> 5;
    if (edge >= N_EDGES) return;
    int lane = tid & 31;
    int row = er[edge]; int col = ec[edge]; float v = ev[edge];
    const float* x = (col < USER_NUM) ? (ue + (size_t)col * EMB)
                                      : (ie + (size_t)(col - USER_NUM) * EMB);
    float4 g = ((const float4*)x)[lane];
    float* o = out + (size_t)row * EMB + lane * 4;
    atomicAdd(o + 0, v * g.x); atomicAdd(o + 1, v * g.y);
    atomicAdd(o + 2, v * g.z); atomicAdd(o + 3, v * g.w);
}
__global__ void spmm_at(const float* __restrict__ x, const float* __restrict__ ev,
                        const int* __restrict__ er, const int* __restrict__ ec,
                        float* __restrict__ out) {
    int tid = blockIdx.x * blockDim.x + threadIdx.x;
    int edge = tid >> 5;
    if (edge >= N_EDGES) return;
    int lane = tid & 31;
    int row = er[edge]; int col = ec[edge]; float v = ev[edge];
    float4 g = ((const float4*)(x + (size_t)col * EMB))[lane];
    float* o = out + (size_t)row * EMB + lane * 4;
    atomicAdd(o + 0, v * g.x); atomicAdd(o + 1, v * g.y);
    atomicAdd(o + 2, v * g.z); atomicAdd(o + 3, v * g.w);
}
__global__ void acc_add(float* __restrict__ acc, const float* __restrict__ cur,
                        float scale, int n4) {
    int i = blockIdx.x * blockDim.x + threadIdx.x;
    if (i >= n4) return;
    float4 a = ((const float4*)acc)[i];
    float4 c = ((const float4*)cur)[i];
    a.x = (a.x + c.x) * scale; a.y = (a.y + c.y) * scale;
    a.z = (a.z + c.z) * scale; a.w = (a.w + c.w) * scale;
    ((float4*)acc)[i] = a;
}

extern "C" void kernel_launch(void* const* d_in, const int* in_sizes, int n_in,
                              void* d_out, int out_size, void* d_ws, size_t ws_size,
                              hipStream_t stream) {
    const float* ue = (const float*)d_in[0];
    const float* ie = (const float*)d_in[1];
    const float* ev = (const float*)d_in[2];
    const int*   er = (const int*)d_in[3];
    const int*   ec = (const int*)d_in[4];
    float* acc = (float*)d_out;

    size_t nfloats = (size_t)N_NODES * EMB;           // 19.2M
    float* buf0 = (float*)d_ws;
    float* buf1 = buf0 + nfloats;

    const int nscan = (N_NODES + SCAN_BS - 1) / SCAN_BS;   // 147
    int*  start  = (int*)(buf1 + nfloats);            // N_NODES+1
    int*  cursor = start + (N_NODES + 1);             // N_NODES
    int2* edges  = (int2*)(cursor + N_NODES);         // N_EDGES packed (c,v)
    int*  bsum   = (int*)(edges + N_EDGES);           // nscan
    size_t needed = (char*)(bsum + nscan) - (char*)d_ws;

    const int BLOCK = 256;
    const int eblocks = (N_EDGES + BLOCK - 1) / BLOCK;

    if (ws_size >= needed) {
        // ---- CSR build ----
        hipMemsetAsync(start, 0, (size_t)N_NODES * sizeof(int), stream);
        hist_k<<<eblocks, BLOCK, 0, stream>>>(er, start);
        scan1_k<<<nscan, SCAN_BS, 0, stream>>>(start, bsum);
        scan2_k<<<1, 64, 0, stream>>>(bsum, nscan);
        scan3_k<<<(N_NODES + BLOCK - 1) / BLOCK, BLOCK, 0, stream>>>(start, cursor, bsum);
        scatter_k<<<eblocks, BLOCK, 0, stream>>>(er, ec, ev, cursor, edges);

        // ---- 3 gather layers ----
        const int gblocks = N_NODES / 8;              // 18750, exact
        spmm_gather<0><<<gblocks, BLOCK, 0, stream>>>(
            nullptr, (const float4*)ue, (const float4*)ie, start, edges,
            (float4*)buf0, nullptr, nullptr);
        spmm_gather<1><<<gblocks, BLOCK, 0, stream>>>(
            (const float4*)buf0, nullptr, nullptr, start, edges,
            (float4*)buf1, nullptr, nullptr);
        spmm_gather<2><<<gblocks, BLOCK, 0, stream>>>(
            (const float4*)buf1, nullptr, nullptr, start, edges,
            nullptr, (const float4*)buf0, (float4*)acc);
    } else {
        // ---- fallback: atomic path ----
        const int spmm_blocks = (N_EDGES * 32) / BLOCK;
        const int n4 = (int)(nfloats / 4);
        const int add_blocks = (n4 + BLOCK - 1) / BLOCK;
        hipMemsetAsync(acc, 0, nfloats * sizeof(float), stream);
        hipMemsetAsync(buf0, 0, nfloats * sizeof(float), stream);
        spmm_first_at<<<spmm_blocks, BLOCK, 0, stream>>>(ue, ie, ev, er, ec, buf0);
        acc_add<<<add_blocks, BLOCK, 0, stream>>>(acc, buf0, 1.0f, n4);
        hipMemsetAsync(buf1, 0, nfloats * sizeof(float), stream);
        spmm_at<<<spmm_blocks, BLOCK, 0, stream>>>(buf0, ev, er, ec, buf1);
        acc_add<<<add_blocks, BLOCK, 0, stream>>>(acc, buf1, 1.0f, n4);
        hipMemsetAsync(buf0, 0, nfloats * sizeof(float), stream);
        spmm_at<<<spmm_blocks, BLOCK, 0, stream>>>(buf1, ev, er, ec, buf0);
        acc_add<<<add_blocks, BLOCK, 0, stream>>>(acc, buf0, 1.0f / 3.0f, n4);
    }
}

// Round 4
// 367.568 us; speedup vs baseline: 8.8364x; 1.0609x over previous
//
#include <hip/hip_runtime.h>

// LightGCN encoder: out = (A·e0 + A²·e0 + A³·e0)/3, A = 600K-edge COO.
// R4 vs R3:
//  (a) gather inner loop processes edges in predicated 4-batches: 4 edge
//      loads then 4 independent 512B gathers in flight (was a serial
//      dependent chain, ~1 gather outstanding -> latency-bound at 2.7 TB/s).
//  (b) scan1/scan2/scan3 fused into ONE kernel via atomic block-base.
//      Segments become non-monotone across blocks, so rows carry (start,cnt)
//      packed int2 instead of relying on start[row+1] adjacency.
constexpr int USER_NUM = 100000;
constexpr int ITEM_NUM = 50000;
constexpr int N_NODES  = USER_NUM + ITEM_NUM;
constexpr int EMB      = 128;
constexpr int N_EDGES  = 600000;
constexpr int SCAN_BS  = 1024;

// ---------------- CSR build ----------------
__global__ void hist_k(const int* __restrict__ er, int* __restrict__ cnt) {
    int e = blockIdx.x * 256 + threadIdx.x;
    if (e < N_EDGES) atomicAdd(&cnt[er[e]], 1);
}

// fused scan: per-block LDS scan + atomic global base. Each row gets a
// contiguous segment [s, s+cnt); segments are disjoint but NOT row-ordered
// across blocks (irrelevant for the gather, which reads (s,cnt) directly).
__global__ __launch_bounds__(SCAN_BS) void scan_fused_k(
        const int* __restrict__ cnt, int* __restrict__ gcount,
        int2* __restrict__ rowinfo, int* __restrict__ cursor) {
    __shared__ int sh[SCAN_BS];
    __shared__ int sbase;
    int i = blockIdx.x * SCAN_BS + threadIdx.x;
    int v = (i < N_NODES) ? cnt[i] : 0;
    sh[threadIdx.x] = v;
    __syncthreads();
    for (int off = 1; off < SCAN_BS; off <<= 1) {
        int t = (threadIdx.x >= off) ? sh[threadIdx.x - off] : 0;
        __syncthreads();
        sh[threadIdx.x] += t;
        __syncthreads();
    }
    if (threadIdx.x == SCAN_BS - 1)
        sbase = atomicAdd(gcount, sh[SCAN_BS - 1]);   // block's exclusive base
    __syncthreads();
    if (i < N_NODES) {
        int s = sbase + sh[threadIdx.x] - v;          // exclusive within block
        rowinfo[i] = make_int2(s, v);
        cursor[i]  = s;
    }
}

// scatter packed (col, val-bits) into row-grouped order: one 8B store/edge
__global__ void scatter_k(const int* __restrict__ er, const int* __restrict__ ec,
                          const float* __restrict__ ev,
                          int* __restrict__ cursor, int2* __restrict__ edges) {
    int e = blockIdx.x * 256 + threadIdx.x;
    if (e >= N_EDGES) return;
    int p = atomicAdd(&cursor[er[e]], 1);
    edges[p] = make_int2(ec[e], __float_as_int(ev[e]));
}

// ---------------- gather SpMM ----------------
// MODE 0: x from the two input tables; out = e1
// MODE 1: x = e1 buffer;               out = e2
// MODE 2: x = e2 buffer; b0 = e1;      acc = (e1+e2+s)/3
template <int MODE>
__global__ __launch_bounds__(256) void spmm_gather(
        const float4* __restrict__ x,
        const float4* __restrict__ ue, const float4* __restrict__ ie,
        const int2* __restrict__ rowinfo, const int2* __restrict__ edges,
        float4* __restrict__ out,
        const float4* __restrict__ b0, float4* __restrict__ acc) {
    int row  = blockIdx.x * 8 + (threadIdx.x >> 5);   // 8 rows / 256-block
    int lane = threadIdx.x & 31;                      // float4 slice of EMB
    int2 ri = rowinfo[row];
    int e0 = ri.x, eend = ri.x + ri.y;
    float4 s = make_float4(0.f, 0.f, 0.f, 0.f);
    for (int base = e0; base < eend; base += 4) {
        // predicated 4-batch: duplicate last edge for short rows (v forced 0)
        int i1 = (base + 1 < eend) ? base + 1 : eend - 1;
        int i2 = (base + 2 < eend) ? base + 2 : eend - 1;
        int i3 = (base + 3 < eend) ? base + 3 : eend - 1;
        int2 p0 = edges[base], p1 = edges[i1], p2 = edges[i2], p3 = edges[i3];
        float v0 = __int_as_float(p0.y);
        float v1 = (base + 1 < eend) ? __int_as_float(p1.y) : 0.f;
        float v2 = (base + 2 < eend) ? __int_as_float(p2.y) : 0.f;
        float v3 = (base + 3 < eend) ? __int_as_float(p3.y) : 0.f;
        const float4 *x0, *x1, *x2, *x3;
        if (MODE == 0) {
            x0 = (p0.x < USER_NUM) ? ue + (size_t)p0.x * 32 : ie + (size_t)(p0.x - USER_NUM) * 32;
            x1 = (p1.x < USER_NUM) ? ue + (size_t)p1.x * 32 : ie + (size_t)(p1.x - USER_NUM) * 32;
            x2 = (p2.x < USER_NUM) ? ue + (size_t)p2.x * 32 : ie + (size_t)(p2.x - USER_NUM) * 32;
            x3 = (p3.x < USER_NUM) ? ue + (size_t)p3.x * 32 : ie + (size_t)(p3.x - USER_NUM) * 32;
        } else {
            x0 = x + (size_t)p0.x * 32;
            x1 = x + (size_t)p1.x * 32;
            x2 = x + (size_t)p2.x * 32;
            x3 = x + (size_t)p3.x * 32;
        }
        // 4 independent 512B gathers in flight
        float4 g0 = x0[lane], g1 = x1[lane], g2 = x2[lane], g3 = x3[lane];
        s.x += v0 * g0.x + v1 * g1.x + v2 * g2.x + v3 * g3.x;
        s.y += v0 * g0.y + v1 * g1.y + v2 * g2.y + v3 * g3.y;
        s.z += v0 * g0.z + v1 * g1.z + v2 * g2.z + v3 * g3.z;
        s.w += v0 * g0.w + v1 * g1.w + v2 * g2.w + v3 * g3.w;
    }
    size_t o = (size_t)row * 32 + lane;
    if (MODE < 2) {
        out[o] = s;
    } else {
        float4 a0 = b0[o];          // e1, linear
        float4 a1 = x[o];           // e2, linear (LLC-warm)
        const float k = 1.0f / 3.0f;
        float4 r;
        r.x = (a0.x + a1.x + s.x) * k;
        r.y = (a0.y + a1.y + s.y) * k;
        r.z = (a0.z + a1.z + s.z) * k;
        r.w = (a0.w + a1.w + s.w) * k;
        acc[o] = r;
    }
}

// ---------------- fallback (atomic path, used only if ws too small) ----
__global__ void spmm_first_at(const float* __restrict__ ue, const float* __restrict__ ie,
                              const float* __restrict__ ev, const int* __restrict__ er,
                              const int* __restrict__ ec, float* __restrict__ out) {
    int tid = blockIdx.x * blockDim.x + threadIdx.x;
    int edge = tid >> 5;
    if (edge >= N_EDGES) return;
    int lane = tid & 31;
    int row = er[edge]; int col = ec[edge]; float v = ev[edge];
    const float* x = (col < USER_NUM) ? (ue + (size_t)col * EMB)
                                      : (ie + (size_t)(col - USER_NUM) * EMB);
    float4 g = ((const float4*)x)[lane];
    float* o = out + (size_t)row * EMB + lane * 4;
    atomicAdd(o + 0, v * g.x); atomicAdd(o + 1, v * g.y);
    atomicAdd(o + 2, v * g.z); atomicAdd(o + 3, v * g.w);
}
__global__ void spmm_at(const float* __restrict__ x, const float* __restrict__ ev,
                        const int* __restrict__ er, const int* __restrict__ ec,
                        float* __restrict__ out) {
    int tid = blockIdx.x * blockDim.x + threadIdx.x;
    int edge = tid >> 5;
    if (edge >= N_EDGES) return;
    int lane = tid & 31;
    int row = er[edge]; int col = ec[edge]; float v = ev[edge];
    float4 g = ((const float4*)(x + (size_t)col * EMB))[lane];
    float* o = out + (size_t)row * EMB + lane * 4;
    atomicAdd(o + 0, v * g.x); atomicAdd(o + 1, v * g.y);
    atomicAdd(o + 2, v * g.z); atomicAdd(o + 3, v * g.w);
}
__global__ void acc_add(float* __restrict__ acc, const float* __restrict__ cur,
                        float scale, int n4) {
    int i = blockIdx.x * blockDim.x + threadIdx.x;
    if (i >= n4) return;
    float4 a = ((const float4*)acc)[i];
    float4 c = ((const float4*)cur)[i];
    a.x = (a.x + c.x) * scale; a.y = (a.y + c.y) * scale;
    a.z = (a.z + c.z) * scale; a.w = (a.w + c.w) * scale;
    ((float4*)acc)[i] = a;
}

extern "C" void kernel_launch(void* const* d_in, const int* in_sizes, int n_in,
                              void* d_out, int out_size, void* d_ws, size_t ws_size,
                              hipStream_t stream) {
    const float* ue = (const float*)d_in[0];
    const float* ie = (const float*)d_in[1];
    const float* ev = (const float*)d_in[2];
    const int*   er = (const int*)d_in[3];
    const int*   ec = (const int*)d_in[4];
    float* acc = (float*)d_out;

    size_t nfloats = (size_t)N_NODES * EMB;           // 19.2M
    float* buf0 = (float*)d_ws;
    float* buf1 = buf0 + nfloats;

    // CSR workspace after the two ping-pong buffers
    int*  cnt     = (int*)(buf1 + nfloats);           // N_NODES
    int*  gcount  = cnt + N_NODES;                    // 1 (zeroed with cnt)
    int2* rowinfo = (int2*)(gcount + 1);              // N_NODES (start,count)
    int*  cursor  = (int*)(rowinfo + N_NODES);        // N_NODES
    int2* edges   = (int2*)(cursor + N_NODES);        // N_EDGES packed (c,v)
    size_t needed = (char*)(edges + N_EDGES) - (char*)d_ws;

    const int BLOCK = 256;
    const int eblocks = (N_EDGES + BLOCK - 1) / BLOCK;
    const int nscan = (N_NODES + SCAN_BS - 1) / SCAN_BS;   // 147

    if (ws_size >= needed) {
        // ---- CSR build: 4 dispatches ----
        hipMemsetAsync(cnt, 0, ((size_t)N_NODES + 1) * sizeof(int), stream);
        hist_k<<<eblocks, BLOCK, 0, stream>>>(er, cnt);
        scan_fused_k<<<nscan, SCAN_BS, 0, stream>>>(cnt, gcount, rowinfo, cursor);
        scatter_k<<<eblocks, BLOCK, 0, stream>>>(er, ec, ev, cursor, edges);

        // ---- 3 gather layers ----
        const int gblocks = N_NODES / 8;              // 18750, exact
        spmm_gather<0><<<gblocks, BLOCK, 0, stream>>>(
            nullptr, (const float4*)ue, (const float4*)ie, rowinfo, edges,
            (float4*)buf0, nullptr, nullptr);
        spmm_gather<1><<<gblocks, BLOCK, 0, stream>>>(
            (const float4*)buf0, nullptr, nullptr, rowinfo, edges,
            (float4*)buf1, nullptr, nullptr);
        spmm_gather<2><<<gblocks, BLOCK, 0, stream>>>(
            (const float4*)buf1, nullptr, nullptr, rowinfo, edges,
            nullptr, (const float4*)buf0, (float4*)acc);
    } else {
        // ---- fallback: atomic path ----
        const int spmm_blocks = (N_EDGES * 32) / BLOCK;
        const int n4 = (int)(nfloats / 4);
        const int add_blocks = (n4 + BLOCK - 1) / BLOCK;
        hipMemsetAsync(acc, 0, nfloats * sizeof(float), stream);
        hipMemsetAsync(buf0, 0, nfloats * sizeof(float), stream);
        spmm_first_at<<<spmm_blocks, BLOCK, 0, stream>>>(ue, ie, ev, er, ec, buf0);
        acc_add<<<add_blocks, BLOCK, 0, stream>>>(acc, buf0, 1.0f, n4);
        hipMemsetAsync(buf1, 0, nfloats * sizeof(float), stream);
        spmm_at<<<spmm_blocks, BLOCK, 0, stream>>>(buf0, ev, er, ec, buf1);
        acc_add<<<add_blocks, BLOCK, 0, stream>>>(acc, buf1, 1.0f, n4);
        hipMemsetAsync(buf0, 0, nfloats * sizeof(float), stream);
        spmm_at<<<spmm_blocks, BLOCK, 0, stream>>>(buf1, ev, er, ec, buf0);
        acc_add<<<add_blocks, BLOCK, 0, stream>>>(acc, buf0, 1.0f / 3.0f, n4);
    }
}

// Round 5
// 311.580 us; speedup vs baseline: 10.4242x; 1.1797x over previous
//
#include <hip/hip_runtime.h>

// LightGCN encoder: out = (A·e0 + A²·e0 + A³·e0)/3, A = 600K-edge COO.
// R5 vs R4:
//  (a) bf16 intermediates: e0 converted once to packed bf16; e1/e2 stored
//      bf16. Per-edge gather 512B -> 256B (8 -> 4 L2 sectors), layer writes
//      halve. Accumulation stays fp32; output fp32. Adds ~5e-5 abs error
//      (threshold 3.8e-4).
//  (b) scatter de-atomized: hist kernel also records rank[e] (old count),
//      scatter stores at rowstart+rank with no atomic.
constexpr int USER_NUM = 100000;
constexpr int ITEM_NUM = 50000;
constexpr int N_NODES  = USER_NUM + ITEM_NUM;
constexpr int EMB      = 128;
constexpr int N_EDGES  = 600000;
constexpr int SCAN_BS  = 1024;

__device__ __forceinline__ float bf2f(unsigned u16) {
    return __uint_as_float(u16 << 16);
}
__device__ __forceinline__ unsigned f2bf(float f) {   // RTNE
    unsigned u = __float_as_uint(f);
    u += 0x7fffu + ((u >> 16) & 1u);
    return u >> 16;
}
__device__ __forceinline__ void fmadd_bf(float4& s, float v, uint2 g) {
    s.x += v * bf2f(g.x & 0xffffu);
    s.y += v * bf2f(g.x >> 16);
    s.z += v * bf2f(g.y & 0xffffu);
    s.w += v * bf2f(g.y >> 16);
}

// ---------------- e0 fp32 -> packed bf16 ----------------
// 8 floats per thread; USER_NUM*EMB/4 is even so both float4s are same-table.
__global__ void conv_k(const float4* __restrict__ ue, const float4* __restrict__ ie,
                       uint4* __restrict__ xb) {
    int i = blockIdx.x * 256 + threadIdx.x;
    const int n = N_NODES * EMB / 8;            // 2.4M
    if (i >= n) return;
    const int u4 = USER_NUM * EMB / 4;          // 3.2M float4s
    int f = 2 * i;
    float4 a, b;
    if (f < u4) { a = ue[f]; b = ue[f + 1]; }
    else        { a = ie[f - u4]; b = ie[f + 1 - u4]; }
    uint4 o;
    o.x = f2bf(a.x) | (f2bf(a.y) << 16);
    o.y = f2bf(a.z) | (f2bf(a.w) << 16);
    o.z = f2bf(b.x) | (f2bf(b.y) << 16);
    o.w = f2bf(b.z) | (f2bf(b.w) << 16);
    xb[i] = o;
}

// ---------------- CSR build ----------------
// histogram + per-edge rank in one pass
__global__ void hist_rank_k(const int* __restrict__ er, int* __restrict__ cnt,
                            int* __restrict__ rank) {
    int e = blockIdx.x * 256 + threadIdx.x;
    if (e < N_EDGES) rank[e] = atomicAdd(&cnt[er[e]], 1);
}

// fused scan: per-block LDS scan + atomic global base -> rowinfo (start,cnt).
// Segments are disjoint but not row-ordered across blocks (irrelevant).
__global__ __launch_bounds__(SCAN_BS) void scan_fused_k(
        const int* __restrict__ cnt, int* __restrict__ gcount,
        int2* __restrict__ rowinfo) {
    __shared__ int sh[SCAN_BS];
    __shared__ int sbase;
    int i = blockIdx.x * SCAN_BS + threadIdx.x;
    int v = (i < N_NODES) ? cnt[i] : 0;
    sh[threadIdx.x] = v;
    __syncthreads();
    for (int off = 1; off < SCAN_BS; off <<= 1) {
        int t = (threadIdx.x >= off) ? sh[threadIdx.x - off] : 0;
        __syncthreads();
        sh[threadIdx.x] += t;
        __syncthreads();
    }
    if (threadIdx.x == SCAN_BS - 1)
        sbase = atomicAdd(gcount, sh[SCAN_BS - 1]);
    __syncthreads();
    if (i < N_NODES)
        rowinfo[i] = make_int2(sbase + sh[threadIdx.x] - v, v);
}

// atomic-free scatter: position = rowstart + precomputed rank
__global__ void scatter_k(const int* __restrict__ er, const int* __restrict__ ec,
                          const float* __restrict__ ev, const int* __restrict__ rank,
                          const int2* __restrict__ rowinfo, int2* __restrict__ edges) {
    int e = blockIdx.x * 256 + threadIdx.x;
    if (e >= N_EDGES) return;
    int p = rowinfo[er[e]].x + rank[e];
    edges[p] = make_int2(ec[e], __float_as_int(ev[e]));
}

// ---------------- gather SpMM (bf16 x, fp32 accumulate) ----------------
// MODE 0/1: out = bf16 layer buffer.
// MODE 2:   s = A*e2; read e1 (b0) and e2 (x) linearly; acc = (e1+e2+s)/3 fp32.
template <int MODE>
__global__ __launch_bounds__(256) void spmm_gather_bf(
        const uint2* __restrict__ x, const int2* __restrict__ rowinfo,
        const int2* __restrict__ edges, uint2* __restrict__ out,
        const uint2* __restrict__ b0, float4* __restrict__ acc) {
    int row  = blockIdx.x * 8 + (threadIdx.x >> 5);   // 8 rows / 256-block
    int lane = threadIdx.x & 31;                      // 4 elems (8B bf16) of EMB
    int2 ri = rowinfo[row];
    int e0 = ri.x, eend = ri.x + ri.y;
    float4 s = make_float4(0.f, 0.f, 0.f, 0.f);
    for (int base = e0; base < eend; base += 4) {
        int i1 = (base + 1 < eend) ? base + 1 : eend - 1;
        int i2 = (base + 2 < eend) ? base + 2 : eend - 1;
        int i3 = (base + 3 < eend) ? base + 3 : eend - 1;
        int2 p0 = edges[base], p1 = edges[i1], p2 = edges[i2], p3 = edges[i3];
        float v0 = __int_as_float(p0.y);
        float v1 = (base + 1 < eend) ? __int_as_float(p1.y) : 0.f;
        float v2 = (base + 2 < eend) ? __int_as_float(p2.y) : 0.f;
        float v3 = (base + 3 < eend) ? __int_as_float(p3.y) : 0.f;
        // 4 independent 256B gathers in flight
        uint2 g0 = x[(size_t)p0.x * 32 + lane];
        uint2 g1 = x[(size_t)p1.x * 32 + lane];
        uint2 g2 = x[(size_t)p2.x * 32 + lane];
        uint2 g3 = x[(size_t)p3.x * 32 + lane];
        fmadd_bf(s, v0, g0);
        fmadd_bf(s, v1, g1);
        fmadd_bf(s, v2, g2);
        fmadd_bf(s, v3, g3);
    }
    size_t o = (size_t)row * 32 + lane;
    if (MODE < 2) {
        uint2 w;
        w.x = f2bf(s.x) | (f2bf(s.y) << 16);
        w.y = f2bf(s.z) | (f2bf(s.w) << 16);
        out[o] = w;
    } else {
        uint2 a0 = b0[o];           // e1, linear bf16
        uint2 a1 = x[o];            // e2, linear bf16 (same buffer we gather)
        const float k = 1.0f / 3.0f;
        float4 r;
        r.x = (s.x + bf2f(a0.x & 0xffffu) + bf2f(a1.x & 0xffffu)) * k;
        r.y = (s.y + bf2f(a0.x >> 16)     + bf2f(a1.x >> 16))     * k;
        r.z = (s.z + bf2f(a0.y & 0xffffu) + bf2f(a1.y & 0xffffu)) * k;
        r.w = (s.w + bf2f(a0.y >> 16)     + bf2f(a1.y >> 16))     * k;
        acc[o] = r;
    }
}

// ---------------- fallback (atomic path, used only if ws too small) ----
__global__ void spmm_first_at(const float* __restrict__ ue, const float* __restrict__ ie,
                              const float* __restrict__ ev, const int* __restrict__ er,
                              const int* __restrict__ ec, float* __restrict__ out) {
    int tid = blockIdx.x * blockDim.x + threadIdx.x;
    int edge = tid >> 5;
    if (edge >= N_EDGES) return;
    int lane = tid & 31;
    int row = er[edge]; int col = ec[edge]; float v = ev[edge];
    const float* x = (col < USER_NUM) ? (ue + (size_t)col * EMB)
                                      : (ie + (size_t)(col - USER_NUM) * EMB);
    float4 g = ((const float4*)x)[lane];
    float* o = out + (size_t)row * EMB + lane * 4;
    atomicAdd(o + 0, v * g.x); atomicAdd(o + 1, v * g.y);
    atomicAdd(o + 2, v * g.z); atomicAdd(o + 3, v * g.w);
}
__global__ void spmm_at(const float* __restrict__ x, const float* __restrict__ ev,
                        const int* __restrict__ er, const int* __restrict__ ec,
                        float* __restrict__ out) {
    int tid = blockIdx.x * blockDim.x + threadIdx.x;
    int edge = tid >> 5;
    if (edge >= N_EDGES) return;
    int lane = tid & 31;
    int row = er[edge]; int col = ec[edge]; float v = ev[edge];
    float4 g = ((const float4*)(x + (size_t)col * EMB))[lane];
    float* o = out + (size_t)row * EMB + lane * 4;
    atomicAdd(o + 0, v * g.x); atomicAdd(o + 1, v * g.y);
    atomicAdd(o + 2, v * g.z); atomicAdd(o + 3, v * g.w);
}
__global__ void acc_add(float* __restrict__ acc, const float* __restrict__ cur,
                        float scale, int n4) {
    int i = blockIdx.x * blockDim.x + threadIdx.x;
    if (i >= n4) return;
    float4 a = ((const float4*)acc)[i];
    float4 c = ((const float4*)cur)[i];
    a.x = (a.x + c.x) * scale; a.y = (a.y + c.y) * scale;
    a.z = (a.z + c.z) * scale; a.w = (a.w + c.w) * scale;
    ((float4*)acc)[i] = a;
}

extern "C" void kernel_launch(void* const* d_in, const int* in_sizes, int n_in,
                              void* d_out, int out_size, void* d_ws, size_t ws_size,
                              hipStream_t stream) {
    const float* ue = (const float*)d_in[0];
    const float* ie = (const float*)d_in[1];
    const float* ev = (const float*)d_in[2];
    const int*   er = (const int*)d_in[3];
    const int*   ec = (const int*)d_in[4];
    float* acc = (float*)d_out;

    size_t nnodes32 = (size_t)N_NODES * 32;           // uint2 per row = 32

    // main-path workspace (bf16 buffers)
    uint2* x0   = (uint2*)d_ws;                       // e0 bf16, 38.4 MB
    uint2* e1b  = x0 + nnodes32;                      // e1 bf16
    uint2* e2b  = e1b + nnodes32;                     // e2 bf16
    int*   cnt  = (int*)(e2b + nnodes32);             // N_NODES
    int*   gcount = cnt + N_NODES;                    // 1 (zeroed with cnt)
    int2*  rowinfo = (int2*)(gcount + 1);             // N_NODES (start,count)
    int*   rank = (int*)(rowinfo + N_NODES);          // N_EDGES
    int2*  edges = (int2*)(rank + N_EDGES);           // N_EDGES packed (c,v)
    size_t needed = (char*)(edges + N_EDGES) - (char*)d_ws;

    const int BLOCK = 256;
    const int eblocks = (N_EDGES + BLOCK - 1) / BLOCK;
    const int nscan = (N_NODES + SCAN_BS - 1) / SCAN_BS;   // 147

    if (ws_size >= needed) {
        // e0 -> bf16 (independent of CSR build)
        const int cvt_n = N_NODES * EMB / 8;
        conv_k<<<(cvt_n + BLOCK - 1) / BLOCK, BLOCK, 0, stream>>>(
            (const float4*)ue, (const float4*)ie, (uint4*)x0);

        // CSR build
        hipMemsetAsync(cnt, 0, ((size_t)N_NODES + 1) * sizeof(int), stream);
        hist_rank_k<<<eblocks, BLOCK, 0, stream>>>(er, cnt, rank);
        scan_fused_k<<<nscan, SCAN_BS, 0, stream>>>(cnt, gcount, rowinfo);
        scatter_k<<<eblocks, BLOCK, 0, stream>>>(er, ec, ev, rank, rowinfo, edges);

        // 3 gather layers
        const int gblocks = N_NODES / 8;              // 18750, exact
        spmm_gather_bf<0><<<gblocks, BLOCK, 0, stream>>>(
            x0, rowinfo, edges, e1b, nullptr, nullptr);
        spmm_gather_bf<1><<<gblocks, BLOCK, 0, stream>>>(
            e1b, rowinfo, edges, e2b, nullptr, nullptr);
        spmm_gather_bf<2><<<gblocks, BLOCK, 0, stream>>>(
            e2b, rowinfo, edges, nullptr, e1b, (float4*)acc);
    } else {
        // fallback: atomic path (fp32 buffers at d_ws)
        size_t nfloats = (size_t)N_NODES * EMB;
        float* buf0 = (float*)d_ws;
        float* buf1 = buf0 + nfloats;
        const int spmm_blocks = (N_EDGES * 32) / BLOCK;
        const int n4 = (int)(nfloats / 4);
        const int add_blocks = (n4 + BLOCK - 1) / BLOCK;
        hipMemsetAsync(acc, 0, nfloats * sizeof(float), stream);
        hipMemsetAsync(buf0, 0, nfloats * sizeof(float), stream);
        spmm_first_at<<<spmm_blocks, BLOCK, 0, stream>>>(ue, ie, ev, er, ec, buf0);
        acc_add<<<add_blocks, BLOCK, 0, stream>>>(acc, buf0, 1.0f, n4);
        hipMemsetAsync(buf1, 0, nfloats * sizeof(float), stream);
        spmm_at<<<spmm_blocks, BLOCK, 0, stream>>>(buf0, ev, er, ec, buf1);
        acc_add<<<add_blocks, BLOCK, 0, stream>>>(acc, buf1, 1.0f, n4);
        hipMemsetAsync(buf0, 0, nfloats * sizeof(float), stream);
        spmm_at<<<spmm_blocks, BLOCK, 0, stream>>>(buf1, ev, er, ec, buf0);
        acc_add<<<add_blocks, BLOCK, 0, stream>>>(acc, buf0, 1.0f / 3.0f, n4);
    }
}